// Round 1
// baseline (34.787 us; speedup 1.0000x reference)
//
#include <hip/hip_runtime.h>
#include <math.h>

#define NP 256      // ids_per_batch
#define NK 16       // imgs_per_id
#define ND 2048     // feature_dim
#define MARGIN 10.0f
#define EPSV 1e-12f

// ---------------------------------------------------------------------------
// K1: per-class center, cc = ||center||^2, intra_max. One block per class p.
// Each thread owns 8 d-columns as two float4 groups (d = j*1024 + t*4).
// ---------------------------------------------------------------------------
__global__ __launch_bounds__(256) void k_center_intra(
    const float* __restrict__ F, float* __restrict__ centers,
    float* __restrict__ cc, float* __restrict__ out) {
  const int p = blockIdx.x;
  const int t = threadIdx.x;

  float acc[NK];
#pragma unroll
  for (int k = 0; k < NK; ++k) acc[k] = 0.f;
  float ccp = 0.f;

#pragma unroll
  for (int j = 0; j < 2; ++j) {
    const int dbase = j * 1024 + t * 4;
    float4 x[NK];
#pragma unroll
    for (int k = 0; k < NK; ++k)
      x[k] = *reinterpret_cast<const float4*>(
          &F[((size_t)(p * NK + k)) * ND + dbase]);
    float4 c;
    c.x = c.y = c.z = c.w = 0.f;
#pragma unroll
    for (int k = 0; k < NK; ++k) {
      c.x += x[k].x; c.y += x[k].y; c.z += x[k].z; c.w += x[k].w;
    }
    const float inv = 1.0f / 16.0f;
    c.x *= inv; c.y *= inv; c.z *= inv; c.w *= inv;
    *reinterpret_cast<float4*>(&centers[(size_t)p * ND + dbase]) = c;
    ccp += c.x * c.x + c.y * c.y + c.z * c.z + c.w * c.w;
#pragma unroll
    for (int k = 0; k < NK; ++k) {
      float dx = x[k].x - c.x, dy = x[k].y - c.y;
      float dz = x[k].z - c.z, dw = x[k].w - c.w;
      acc[k] += dx * dx + dy * dy + dz * dz + dw * dw;
    }
  }

  // wave-level butterfly reduce (wave = 64 lanes)
#pragma unroll
  for (int k = 0; k < NK; ++k) {
    float v = acc[k];
#pragma unroll
    for (int m = 32; m > 0; m >>= 1) v += __shfl_xor(v, m);
    acc[k] = v;
  }
  {
    float v = ccp;
#pragma unroll
    for (int m = 32; m > 0; m >>= 1) v += __shfl_xor(v, m);
    ccp = v;
  }

  __shared__ float red[4][NK + 1];
  const int wave = t >> 6, lane = t & 63;
  if (lane == 0) {
#pragma unroll
    for (int k = 0; k < NK; ++k) red[wave][k] = acc[k];
    red[wave][NK] = ccp;
  }
  __syncthreads();
  if (t == 0) {
    float m = 0.f;
#pragma unroll
    for (int k = 0; k < NK; ++k) {
      float s = red[0][k] + red[1][k] + red[2][k] + red[3][k];
      m = fmaxf(m, sqrtf(fmaxf(s, EPSV)));
    }
    out[1 + p] = m;  // intra_max
    cc[p] = red[0][NK] + red[1][NK] + red[2][NK] + red[3][NK];
  }
}

// ---------------------------------------------------------------------------
// K2: G += C_tile * C_tile^T  (64x64 tile, split-K=16, BK=128)
// 256 threads, 4x4 micro-tile; micro rows strided by 16 so LDS b128 reads
// across a wave hit distinct bank groups (<=2-way conflict = free).
// ---------------------------------------------------------------------------
#define BK 128
#define LDP 132  // padded row stride (floats), 16B-aligned rows

__global__ __launch_bounds__(256) void k_gemm(
    const float* __restrict__ C, float* __restrict__ G) {
  __shared__ float As[64][LDP];
  __shared__ float Bs[64][LDP];
  const int t = threadIdx.x;
  const int p0 = blockIdx.x * 64;
  const int q0 = blockIdx.y * 64;
  const int k0 = blockIdx.z * BK;

  // stage 64x128 panels of A-rows (p0..) and B-rows (q0..), coalesced float4
#pragma unroll
  for (int rep = 0; rep < 8; ++rep) {
    const int idx = rep * 256 + t;  // 0..2047
    const int r = idx >> 5;         // row 0..63
    const int c4 = idx & 31;        // float4 col 0..31
    float4 a = *reinterpret_cast<const float4*>(
        &C[(size_t)(p0 + r) * ND + k0 + c4 * 4]);
    float4 b = *reinterpret_cast<const float4*>(
        &C[(size_t)(q0 + r) * ND + k0 + c4 * 4]);
    *reinterpret_cast<float4*>(&As[r][c4 * 4]) = a;
    *reinterpret_cast<float4*>(&Bs[r][c4 * 4]) = b;
  }
  __syncthreads();

  const int ti = t >> 4;  // 0..15
  const int tj = t & 15;  // 0..15
  float acc[4][4] = {};

#pragma unroll
  for (int kk = 0; kk < BK; kk += 4) {
    float4 a4[4], b4[4];
#pragma unroll
    for (int u = 0; u < 4; ++u)
      a4[u] = *reinterpret_cast<const float4*>(&As[ti + u * 16][kk]);
#pragma unroll
    for (int v = 0; v < 4; ++v)
      b4[v] = *reinterpret_cast<const float4*>(&Bs[tj + v * 16][kk]);
#pragma unroll
    for (int u = 0; u < 4; ++u)
#pragma unroll
      for (int v = 0; v < 4; ++v)
        acc[u][v] += a4[u].x * b4[v].x + a4[u].y * b4[v].y +
                     a4[u].z * b4[v].z + a4[u].w * b4[v].w;
  }

#pragma unroll
  for (int u = 0; u < 4; ++u)
#pragma unroll
    for (int v = 0; v < 4; ++v)
      atomicAdd(&G[(size_t)(p0 + ti + u * 16) * NP + q0 + tj + v * 16],
                acc[u][v]);
}

// ---------------------------------------------------------------------------
// K3: inter_min[p] = min_{q != p} sqrt(max(cc[p]+cc[q]-2G[p][q], EPS))
// ---------------------------------------------------------------------------
__global__ __launch_bounds__(256) void k_inter(
    const float* __restrict__ G, const float* __restrict__ cc,
    float* __restrict__ out) {
  const int p = blockIdx.x, q = threadIdx.x;
  const float g = G[(size_t)p * NP + q];
  const float cd2 = cc[p] + cc[q] - 2.0f * g;
  float cd = (q == p) ? INFINITY : sqrtf(fmaxf(cd2, EPSV));
#pragma unroll
  for (int m = 32; m > 0; m >>= 1) cd = fminf(cd, __shfl_xor(cd, m));
  __shared__ float red[4];
  if ((q & 63) == 0) red[q >> 6] = cd;
  __syncthreads();
  if (q == 0)
    out[1 + NP + p] =
        fminf(fminf(red[0], red[1]), fminf(red[2], red[3]));
}

// ---------------------------------------------------------------------------
// K4: loss = mean(relu(intra_max - inter_min + MARGIN))
// ---------------------------------------------------------------------------
__global__ __launch_bounds__(256) void k_loss(float* __restrict__ out) {
  const int t = threadIdx.x;
  const float im = out[1 + t];
  const float in_ = out[1 + NP + t];
  float v = fmaxf(im - in_ + MARGIN, 0.f);
#pragma unroll
  for (int m = 32; m > 0; m >>= 1) v += __shfl_xor(v, m);
  __shared__ float red[4];
  if ((t & 63) == 0) red[t >> 6] = v;
  __syncthreads();
  if (t == 0) out[0] = (red[0] + red[1] + red[2] + red[3]) / (float)NP;
}

// ---------------------------------------------------------------------------
extern "C" void kernel_launch(void* const* d_in, const int* in_sizes, int n_in,
                              void* d_out, int out_size, void* d_ws,
                              size_t ws_size, hipStream_t stream) {
  const float* F = (const float*)d_in[0];  // features [4096, 2048] fp32
  float* out = (float*)d_out;              // [513]: loss, intra_max, inter_min

  float* centers = (float*)d_ws;                    // 256*2048 fp32 (2 MB)
  float* cc = centers + (size_t)NP * ND;            // 256 fp32
  float* G = cc + NP;                               // 256*256 fp32 (256 KB)

  hipMemsetAsync(G, 0, (size_t)NP * NP * sizeof(float), stream);
  k_center_intra<<<NP, 256, 0, stream>>>(F, centers, cc, out);
  k_gemm<<<dim3(4, 4, 16), 256, 0, stream>>>(centers, G);
  k_inter<<<NP, 256, 0, stream>>>(G, cc, out);
  k_loss<<<1, 256, 0, stream>>>(out);
}